// Round 11
// baseline (817.206 us; speedup 1.0000x reference)
//
#include <hip/hip_runtime.h>
#include <hip/hip_cooperative_groups.h>

namespace cg = cooperative_groups;

// Spatially varying anisotropic 2D elastic wave sim, 384x384, 192 steps.
// Round 10: PERSISTENT cooperative kernel. One dispatch; 16 epochs of K=12
// steps with grid.sync() between epochs (15 grid syncs total).
//  - coeffs loaded ONCE into registers for the whole run (R8 reloaded 16x)
//  - owned threads keep cur/old in REGISTERS across epochs; only the halo
//    ring's state is re-read per epoch (9 float4 loads for 75% of threads)
//  - state ping-pongs by epoch parity (kills cross-block write/read race;
//    single grid.sync per epoch boundary is then sufficient ordering)
//  - step loop identical to R8: 48x48 staging, packed v2f LDS + pk math,
//    lgkm-only barrier, fire-and-forget frame stores

typedef float v2f __attribute__((ext_vector_type(2)));

#define NXg 384
#define NYg 384
#define NPT (NXg * NYg)
#define NFRAMES 48

#define OWN 24
#define HALO 12
#define TS 48
#define KSTEPS 12
#define NEPOCH 16

#define H_   1e-4
#define DT_  5e-9
#define RHO_ 1610.0

#define B11_LO 5e10f
#define B11_HI 2.5e11f
#define B22_LO 5e9f
#define B22_HI 5e10f
#define B12_LO 5e9f
#define B12_HI 5e10f
#define B16_LO 0.0f
#define B16_HI 6e10f
#define B26_LO 0.0f
#define B26_HI 2e10f
#define B66_LO 5e9f
#define B66_HI 3e10f

static __device__ __constant__ float kScale  = (float)(DT_ * DT_ / (H_ * H_) / RHO_);
static __device__ __constant__ float kSrcScl = (float)(DT_ * DT_ / RHO_);

__device__ __forceinline__ float clipf(float v, float lo, float hi) {
    return fminf(fmaxf(v, lo), hi);
}
__device__ __forceinline__ v2f vfma(v2f a, v2f b, v2f c) {
    return __builtin_elementwise_fma(a, b, c);
}
__device__ __forceinline__ v2f vbc(float s) { v2f r; r[0] = s; r[1] = s; return r; }
__device__ __forceinline__ v2f vswap(v2f a) { return __builtin_shufflevector(a, a, 1, 0); }

// barrier that only waits LDS (no vmcnt drain)
#define LDS_BARRIER() asm volatile("s_waitcnt lgkmcnt(0)\n\ts_barrier" ::: "memory")

// ws float layout:
// [0..4NPT):    C0 = float4{A11, A22, A12p66, A16}  (pre-scaled)
// [4NPT..8NPT): C1 = float4{A26, A66, GS, 0}
// [8NPT..12NPT):  state buf0: float4{cur.x, cur.y, old.x, old.y}
// [12NPT..16NPT): state buf1

__global__ __launch_bounds__(256)
void setup_kernel(const float* __restrict__ lc11, const float* __restrict__ lc12,
                  const float* __restrict__ lc16, const float* __restrict__ lc22,
                  const float* __restrict__ lc26, const float* __restrict__ lc66,
                  const float* __restrict__ gauss, float* __restrict__ ws) {
    int i = blockIdx.x * blockDim.x + threadIdx.x;
    if (i >= NPT) return;
    float C11 = clipf(expf(lc11[i]), B11_LO, B11_HI);
    float C12 = clipf(expf(lc12[i]), B12_LO, B12_HI);
    float C16 = clipf(expf(lc16[i]), B16_LO, B16_HI);
    float C22 = clipf(expf(lc22[i]), B22_LO, B22_HI);
    float C26 = clipf(expf(lc26[i]), B26_LO, B26_HI);
    float C66 = clipf(expf(lc66[i]), B66_LO, B66_HI);
    float s = kScale;
    float4* C0 = (float4*)ws;
    float4* C1 = (float4*)(ws + 4 * (size_t)NPT);
    C0[i] = make_float4(C11 * s, C22 * s, (C12 + C66) * s, C16 * s);
    C1[i] = make_float4(C26 * s, C66 * s, gauss[i] * kSrcScl, 0.0f);
    float4* s0 = (float4*)(ws + 8 * (size_t)NPT);
    float4* s1 = (float4*)(ws + 12 * (size_t)NPT);
    s0[i] = make_float4(0.0f, 0.0f, 0.0f, 0.0f);
    s1[i] = make_float4(0.0f, 0.0f, 0.0f, 0.0f);
}

__global__ __launch_bounds__(256, 1)
void persist_kernel(float* __restrict__ ws, const float* __restrict__ sig,
                    float* __restrict__ out) {
    cg::grid_group grid = cg::this_grid();

    __shared__ v2f sb[2][TS][TS + 1];

    const int tid = threadIdx.x;
    const int tx = tid >> 4;
    const int ty = tid & 15;
    const int r0 = 3 * tx;
    const int c0 = 3 * ty;
    const int gx0 = blockIdx.y * OWN - HALO;
    const int gy0 = blockIdx.x * OWN - HALO;

    const float4* __restrict__ C0 = (const float4*)ws;
    const float4* __restrict__ C1 = (const float4*)(ws + 4 * (size_t)NPT);
    float4* __restrict__ st[2];
    st[0] = (float4*)(ws + 8 * (size_t)NPT);
    st[1] = (float4*)(ws + 12 * (size_t)NPT);

    v2f cur[9], old_[9];
    v2f ca[9], cb[9];                       // {A11,A66}, {A66,A22}
    float a12p66[9], a16[9], a26[9], gs[9];
    int gidx[9];
    bool dom[9];

    // ---- one-time coeff load (lives in registers for all 192 steps) ----
#pragma unroll
    for (int i = 0; i < 3; ++i) {
#pragma unroll
        for (int j = 0; j < 3; ++j) {
            int p = i * 3 + j;
            int gx = gx0 + r0 + i;
            int gy = gy0 + c0 + j;
            bool d = (unsigned)gx < (unsigned)NXg && (unsigned)gy < (unsigned)NYg;
            int g = d ? gx * NYg + gy : 0;
            gidx[p] = g; dom[p] = d;
            float4 k0 = d ? C0[g] : make_float4(0, 0, 0, 0);
            float4 k1 = d ? C1[g] : make_float4(0, 0, 0, 0);
            v2f t; t[0] = k0.x; t[1] = k1.y; ca[p] = t;   // {A11, A66}
            v2f u; u[0] = k1.y; u[1] = k0.y; cb[p] = u;   // {A66, A22}
            a12p66[p] = k0.z; a16[p] = k0.w; a26[p] = k1.x; gs[p] = k1.z;
            cur[p] = vbc(0.0f);
            old_[p] = vbc(0.0f);
        }
    }

    // clamped halo coords (trapezoid garbage-tolerance at staging rim)
    const int rm = (r0 > 0) ? r0 - 1 : 0;
    const int rp = (r0 + 3 < TS) ? r0 + 3 : TS - 1;
    const int cm = (c0 > 0) ? c0 - 1 : 0;
    const int cp = (c0 + 3 < TS) ? c0 + 3 : TS - 1;

    const bool owned = (tx >= 4) && (tx < 12) && (ty >= 4) && (ty < 12);

    v2f c20; c20[0] = 2.0f; c20[1] = 0.0f;
    v2f c02; c02[0] = 0.0f; c02[1] = 2.0f;
    const v2f m2 = vbc(-2.0f);
    const v2f qt = vbc(0.25f);
    const v2f two = vbc(2.0f);

#pragma unroll 1
    for (int e = 0; e < NEPOCH; ++e) {
        // ---- epoch prologue: halo threads reload state (owners keep regs)
        // epoch e reads buf[(e-1)&1]; epoch 0 reads buf1 == zeros.
        if (!owned) {
            const float4* __restrict__ rs = st[(e + 1) & 1];
#pragma unroll
            for (int p = 0; p < 9; ++p) {
                float4 s4 = dom[p] ? rs[gidx[p]] : make_float4(0, 0, 0, 0);
                v2f c; c[0] = s4.x; c[1] = s4.y;
                v2f o; o[0] = s4.z; o[1] = s4.w;
                cur[p] = c; old_[p] = o;
            }
        }
        const int t0 = e * KSTEPS;
        float sigv[KSTEPS];
#pragma unroll
        for (int k = 0; k < KSTEPS; ++k) sigv[k] = sig[t0 + k];

        // publish initial values into buffer 0
#pragma unroll
        for (int i = 0; i < 3; ++i)
#pragma unroll
            for (int j = 0; j < 3; ++j)
                sb[0][r0 + i][c0 + j] = cur[i * 3 + j];
        LDS_BARRIER();

#pragma unroll 1
        for (int s = 1; s <= KSTEPS; ++s) {
            const v2f (*rb)[TS + 1] = sb[(s - 1) & 1];
            v2f (*wb)[TS + 1] = sb[s & 1];
            v2f vsig; vsig[0] = 0.0f; vsig[1] = sigv[s - 1];

            // assemble 5x5 v2f window: own 3x3 from regs + 16 halo b64 reads
            v2f v[5][5];
#pragma unroll
            for (int i = 0; i < 3; ++i)
#pragma unroll
                for (int j = 0; j < 3; ++j)
                    v[i + 1][j + 1] = cur[i * 3 + j];
            v[0][0] = rb[rm][cm];  v[0][4] = rb[rm][cp];
            v[4][0] = rb[rp][cm];  v[4][4] = rb[rp][cp];
#pragma unroll
            for (int j = 0; j < 3; ++j) {
                v[0][j + 1] = rb[rm][c0 + j];
                v[4][j + 1] = rb[rp][c0 + j];
                v[j + 1][0] = rb[r0 + j][cm];
                v[j + 1][4] = rb[r0 + j][cp];
            }

            // horizontal differences shared across the 9 points
            v2f dh[5][3];
#pragma unroll
            for (int i = 0; i < 5; ++i)
#pragma unroll
                for (int j = 0; j < 3; ++j)
                    dh[i][j] = v[i][j + 2] - v[i][j];

#pragma unroll
            for (int i = 0; i < 3; ++i)
#pragma unroll
                for (int j = 0; j < 3; ++j) {
                    int p = i * 3 + j;
                    v2f c = v[i + 1][j + 1];
                    v2f sxx = vfma(m2, c, v[i][j + 1] + v[i + 2][j + 1]);
                    v2f syy = vfma(m2, c, v[i + 1][j] + v[i + 1][j + 2]);
                    v2f sxy = qt * (dh[i + 2][j] - dh[i][j]);

                    v2f t4 = vfma(c20, vbc(sxy[0]), vswap(sxx));
                    v2f t5 = vfma(c02, vbc(sxy[1]), vswap(syy));
                    v2f Lv = ca[p] * sxx;
                    Lv = vfma(cb[p], syy, Lv);
                    Lv = vfma(vbc(a12p66[p]), vswap(sxy), Lv);
                    Lv = vfma(vbc(a16[p]), t4, Lv);
                    Lv = vfma(vbc(a26[p]), t5, Lv);
                    Lv = vfma(vsig, vbc(gs[p]), Lv);   // {lux, sig*gs + luy}
                    v2f n = vfma(two, c, Lv) - old_[p];
                    old_[p] = c;
                    cur[p] = n;
                }

            // frame output at global t = t0 + s - 1; t%4==3 <=> s%4==0
            // (fire-and-forget: step barrier does NOT drain vmcnt)
            if ((s & 3) == 0 && owned) {
                int f = 3 * e + (s >> 2) - 1;
                float* oux = out + (size_t)f * NPT;
                float* ouy = out + (size_t)(NFRAMES + f) * NPT;
#pragma unroll
                for (int p = 0; p < 9; ++p) {
                    oux[gidx[p]] = cur[p][0];
                    ouy[gidx[p]] = cur[p][1];
                }
            }

            // publish new values; ONE lgkm-only barrier per step
#pragma unroll
            for (int i = 0; i < 3; ++i)
#pragma unroll
                for (int j = 0; j < 3; ++j)
                    wb[r0 + i][c0 + j] = cur[i * 3 + j];
            LDS_BARRIER();
        }

        // ---- epoch epilogue: owners publish state for neighbors' next epoch
        if (e + 1 < NEPOCH) {
            if (owned) {
                float4* __restrict__ wsbuf = st[e & 1];
#pragma unroll
                for (int p = 0; p < 9; ++p) {
                    float4 s4 = make_float4(cur[p][0], cur[p][1],
                                            old_[p][0], old_[p][1]);
                    wsbuf[gidx[p]] = s4;
                }
            }
            grid.sync();   // release stores + grid-wide barrier
        }
    }
}

extern "C" void kernel_launch(void* const* d_in, const int* in_sizes, int n_in,
                              void* d_out, int out_size, void* d_ws, size_t ws_size,
                              hipStream_t stream) {
    const float* lc11  = (const float*)d_in[0];
    const float* lc12  = (const float*)d_in[1];
    const float* lc16  = (const float*)d_in[2];
    const float* lc22  = (const float*)d_in[3];
    const float* lc26  = (const float*)d_in[4];
    const float* lc66  = (const float*)d_in[5];
    const float* gauss = (const float*)d_in[6];
    const float* sig   = (const float*)d_in[7];

    float* ws  = (float*)d_ws;
    float* out = (float*)d_out;

    setup_kernel<<<(NPT + 255) / 256, 256, 0, stream>>>(lc11, lc12, lc16, lc22,
                                                        lc26, lc66, gauss, ws);

    void* args[] = {(void*)&ws, (void*)&sig, (void*)&out};
    dim3 grid(NXg / OWN, NYg / OWN);  // 16x16 = 256 blocks, 1 per CU
    hipLaunchCooperativeKernel((void*)persist_kernel, grid, dim3(256), args, 0,
                               stream);
}

// Round 12
// 391.441 us; speedup vs baseline: 2.0877x; 2.0877x over previous
//
#include <hip/hip_runtime.h>

// Spatially varying anisotropic 2D elastic wave sim, 384x384, 192 steps.
// Round 11: DPP register-shuffle stencil (R10 counters: step loop is ~90%
// LDS-roundtrip/barrier wait, VALUBusy 10%).
//  - R8 macro-geometry: 256 blocks (1/CU), 16 launches, TS=48, K=12, OWN=24
//  - each of 4 waves owns a 12-row x 48-col slab; LANE = COLUMN
//  - horizontal neighbors via v_mov_dpp wave_shr1/wave_shl1 (VALU pipe,
//    zero LDS); vertical neighbors are register rows; only 2 slab-boundary
//    rows/wave exchanged via LDS per step (2 wr + 2 rd + 1 lgkm barrier,
//    was 25 ops + barrier)
//  - cur/old + coeffs for 12 rows live in VGPRs (~210, 1 wave/SIMD is fine)
//  - rolling pipeline carries pre-update D=SL-SR and S=SL+SR of rows
//  - arithmetic chain identical to R8 (verified absmax 1.2e-4)

typedef float v2f __attribute__((ext_vector_type(2)));

#define NXg 384
#define NYg 384
#define NPT (NXg * NYg)
#define NFRAMES 48

#define OWN 24
#define HALO 12
#define TS 48
#define KSTEPS 12
#define NLAUNCH 16
#define ROWS 12        // rows per wave slab

#define H_   1e-4
#define DT_  5e-9
#define RHO_ 1610.0

#define B11_LO 5e10f
#define B11_HI 2.5e11f
#define B22_LO 5e9f
#define B22_HI 5e10f
#define B12_LO 5e9f
#define B12_HI 5e10f
#define B16_LO 0.0f
#define B16_HI 6e10f
#define B26_LO 0.0f
#define B26_HI 2e10f
#define B66_LO 5e9f
#define B66_HI 3e10f

static __device__ __constant__ float kScale  = (float)(DT_ * DT_ / (H_ * H_) / RHO_);
static __device__ __constant__ float kSrcScl = (float)(DT_ * DT_ / RHO_);

__device__ __forceinline__ float clipf(float v, float lo, float hi) {
    return fminf(fmaxf(v, lo), hi);
}
__device__ __forceinline__ v2f vfma(v2f a, v2f b, v2f c) {
    return __builtin_elementwise_fma(a, b, c);
}
__device__ __forceinline__ v2f vbc(float s) { v2f r; r[0] = s; r[1] = s; return r; }
__device__ __forceinline__ v2f vswap(v2f a) { return __builtin_shufflevector(a, a, 1, 0); }

// DPP lane shifts: wave_shr1 (0x138): lane i <- lane i-1; wave_shl1 (0x130):
// lane i <- lane i+1. old=0 => boundary lanes read 0 either bound_ctrl way.
__device__ __forceinline__ float dpp_from_lo(float x) {   // value at col c-1
    int v = __builtin_amdgcn_update_dpp(0, __builtin_bit_cast(int, x),
                                        0x138, 0xf, 0xf, true);
    return __builtin_bit_cast(float, v);
}
__device__ __forceinline__ float dpp_from_hi(float x) {   // value at col c+1
    int v = __builtin_amdgcn_update_dpp(0, __builtin_bit_cast(int, x),
                                        0x130, 0xf, 0xf, true);
    return __builtin_bit_cast(float, v);
}
__device__ __forceinline__ v2f shiftL(v2f a) {  // per-lane: value from col c-1
    v2f r; r[0] = dpp_from_lo(a[0]); r[1] = dpp_from_lo(a[1]); return r;
}
__device__ __forceinline__ v2f shiftR(v2f a) {  // per-lane: value from col c+1
    v2f r; r[0] = dpp_from_hi(a[0]); r[1] = dpp_from_hi(a[1]); return r;
}

// barrier that only waits LDS (no vmcnt drain)
#define LDS_BARRIER() asm volatile("s_waitcnt lgkmcnt(0)\n\ts_barrier" ::: "memory")

// ws float layout:
// [0..4NPT):    C0 = float4{A11, A22, A12p66, A16}  (pre-scaled)
// [4NPT..8NPT): C1 = float4{A26, A66, GS, 0}
// [8NPT..12NPT):  state set0: float4{cur.x, cur.y, old.x, old.y}
// [12NPT..16NPT): state set1

__global__ __launch_bounds__(256)
void setup_kernel(const float* __restrict__ lc11, const float* __restrict__ lc12,
                  const float* __restrict__ lc16, const float* __restrict__ lc22,
                  const float* __restrict__ lc26, const float* __restrict__ lc66,
                  const float* __restrict__ gauss, float* __restrict__ ws) {
    int i = blockIdx.x * blockDim.x + threadIdx.x;
    if (i >= NPT) return;
    float C11 = clipf(expf(lc11[i]), B11_LO, B11_HI);
    float C12 = clipf(expf(lc12[i]), B12_LO, B12_HI);
    float C16 = clipf(expf(lc16[i]), B16_LO, B16_HI);
    float C22 = clipf(expf(lc22[i]), B22_LO, B22_HI);
    float C26 = clipf(expf(lc26[i]), B26_LO, B26_HI);
    float C66 = clipf(expf(lc66[i]), B66_LO, B66_HI);
    float s = kScale;
    float4* C0 = (float4*)ws;
    float4* C1 = (float4*)(ws + 4 * (size_t)NPT);
    C0[i] = make_float4(C11 * s, C22 * s, (C12 + C66) * s, C16 * s);
    C1[i] = make_float4(C26 * s, C66 * s, gauss[i] * kSrcScl, 0.0f);
    float4* s0 = (float4*)(ws + 8 * (size_t)NPT);
    s0[i] = make_float4(0.0f, 0.0f, 0.0f, 0.0f);
}

__global__ __launch_bounds__(256, 1)
void fused_kernel(const float* __restrict__ ws, const float* __restrict__ sig,
                  const float4* __restrict__ inS, float4* __restrict__ outS,
                  float* __restrict__ out, int L) {
    // slab-boundary exchange: xch[buf][wave][top/bot][lane]
    __shared__ v2f xch[2][4][2][64];

    const int tid = threadIdx.x;
    const int w = tid >> 6;           // wave 0..3: rows [12w, 12w+12)
    const int c = tid & 63;           // lane = staging column (0..47 used)
    const int gx0 = (int)blockIdx.y * OWN - HALO;
    const int gy = (int)blockIdx.x * OWN - HALO + c;

    const float4* __restrict__ C0 = (const float4*)ws;
    const float4* __restrict__ C1 = (const float4*)(ws + 4 * (size_t)NPT);

    v2f cur[ROWS], old_[ROWS];
    v2f ca[ROWS], cb[ROWS];           // {A11,A66}, {A66,A22}
    float a12p66[ROWS], a16[ROWS], a26[ROWS], gs[ROWS];
    int g[ROWS];

    const bool colOk = (c < TS) && ((unsigned)gy < (unsigned)NYg);
#pragma unroll
    for (int r = 0; r < ROWS; ++r) {
        int gx = gx0 + ROWS * w + r;
        bool d = colOk && ((unsigned)gx < (unsigned)NXg);
        int gg = d ? gx * NYg + gy : 0;
        g[r] = gg;
        float4 st = d ? inS[gg] : make_float4(0, 0, 0, 0);
        v2f cc; cc[0] = st.x; cc[1] = st.y;
        v2f oo; oo[0] = st.z; oo[1] = st.w;
        cur[r] = cc; old_[r] = oo;
        // out-of-domain -> zero coeffs => point stays exactly 0 (= boundary)
        float4 k0 = d ? C0[gg] : make_float4(0, 0, 0, 0);
        float4 k1 = d ? C1[gg] : make_float4(0, 0, 0, 0);
        v2f t; t[0] = k0.x; t[1] = k1.y; ca[r] = t;    // {A11, A66}
        v2f u; u[0] = k1.y; u[1] = k0.y; cb[r] = u;    // {A66, A22}
        a12p66[r] = k0.z; a16[r] = k0.w; a26[r] = k1.x; gs[r] = k1.z;
    }

    const int t0 = L * KSTEPS;
    float sigv[KSTEPS];
#pragma unroll
    for (int k = 0; k < KSTEPS; ++k) sigv[k] = sig[t0 + k];

    // owned region: staging rows [12,36) (waves 1,2), cols [12,36)
    const bool ownW = (w == 1) || (w == 2);
    const bool ownC = (c >= HALO) && (c < HALO + OWN);
    const int wa = (w > 0) ? w - 1 : w;   // clamped neighbor indices
    const int wb = (w < 3) ? w + 1 : w;

    v2f c20; c20[0] = 2.0f; c20[1] = 0.0f;
    v2f c02; c02[0] = 0.0f; c02[1] = 2.0f;
    const v2f m2 = vbc(-2.0f);
    const v2f qt = vbc(0.25f);
    const v2f two = vbc(2.0f);

#pragma unroll 1
    for (int s = 1; s <= KSTEPS; ++s) {
        // ---- slab-boundary exchange: 2 writes + 1 barrier + 2 reads ----
        v2f (*xb)[2][64] = xch[s & 1];
        xb[w][0][c] = cur[0];
        xb[w][1][c] = cur[ROWS - 1];
        LDS_BARRIER();
        v2f Ba = xb[wa][1][c];               // row above slab (pre-update)
        v2f Bb = xb[wb][0][c];               // row below slab (pre-update)
        if (w == 0) Ba = vbc(0.0f);          // staging row -1: outside
        if (w == 3) Bb = vbc(0.0f);          // staging row 48: outside

        v2f vsig; vsig[0] = 0.0f; vsig[1] = sigv[s - 1];

        // ---- prime rolling pipeline (pre-update D = SL-SR, S = SL+SR) ----
        v2f slA = shiftL(Ba), srA = shiftR(Ba);
        v2f Dprev = slA - srA;
        v2f below_prev = Ba;                 // pre-update value of row r-1
        v2f sl0 = shiftL(cur[0]), sr0 = shiftR(cur[0]);
        v2f Dcur = sl0 - sr0;
        v2f Scur = sl0 + sr0;

#pragma unroll
        for (int r = 0; r < ROWS; ++r) {
            v2f nxt = (r < ROWS - 1) ? cur[r + 1] : Bb;   // pre-update row r+1
            v2f sln = shiftL(nxt), srn = shiftR(nxt);
            v2f Dnext = sln - srn;
            v2f Snext = sln + srn;

            v2f cc = cur[r];
            v2f sxx = vfma(m2, cc, below_prev + nxt);     // vertical 2nd diff
            v2f syy = vfma(m2, cc, Scur);                 // horizontal 2nd diff
            v2f sxy = qt * (Dprev - Dnext);               // cross derivative

            v2f t4 = vfma(c20, vbc(sxy[0]), vswap(sxx));
            v2f t5 = vfma(c02, vbc(sxy[1]), vswap(syy));
            v2f Lv = ca[r] * sxx;
            Lv = vfma(cb[r], syy, Lv);
            Lv = vfma(vbc(a12p66[r]), vswap(sxy), Lv);
            Lv = vfma(vbc(a16[r]), t4, Lv);
            Lv = vfma(vbc(a26[r]), t5, Lv);
            Lv = vfma(vsig, vbc(gs[r]), Lv);              // {lux, sig*gs+luy}
            v2f n = vfma(two, cc, Lv) - old_[r];

            old_[r] = cc;
            cur[r] = n;
            below_prev = cc;
            Dprev = Dcur; Dcur = Dnext; Scur = Snext;
        }

        // ---- frame output: t = t0+s-1; t%4==3 <=> s%4==0 (fire-and-forget)
        if ((s & 3) == 0 && ownW && ownC) {
            int f = 3 * L + (s >> 2) - 1;
            float* oux = out + (size_t)f * NPT;
            float* ouy = out + (size_t)(NFRAMES + f) * NPT;
#pragma unroll
            for (int r = 0; r < ROWS; ++r) {
                oux[g[r]] = cur[r][0];
                ouy[g[r]] = cur[r][1];
            }
        }
    }

    // ---- epilogue: owned threads publish state for the next launch ----
    if (ownW && ownC) {
#pragma unroll
        for (int r = 0; r < ROWS; ++r)
            outS[g[r]] = make_float4(cur[r][0], cur[r][1],
                                     old_[r][0], old_[r][1]);
    }
}

extern "C" void kernel_launch(void* const* d_in, const int* in_sizes, int n_in,
                              void* d_out, int out_size, void* d_ws, size_t ws_size,
                              hipStream_t stream) {
    const float* lc11  = (const float*)d_in[0];
    const float* lc12  = (const float*)d_in[1];
    const float* lc16  = (const float*)d_in[2];
    const float* lc22  = (const float*)d_in[3];
    const float* lc26  = (const float*)d_in[4];
    const float* lc66  = (const float*)d_in[5];
    const float* gauss = (const float*)d_in[6];
    const float* sig   = (const float*)d_in[7];

    float* ws  = (float*)d_ws;
    float* out = (float*)d_out;

    setup_kernel<<<(NPT + 255) / 256, 256, 0, stream>>>(lc11, lc12, lc16, lc22,
                                                        lc26, lc66, gauss, ws);

    float4* set0 = (float4*)(ws + 8 * (size_t)NPT);
    float4* set1 = (float4*)(ws + 12 * (size_t)NPT);

    dim3 grid(NXg / OWN, NYg / OWN);  // 16x16 = 256 blocks, 1 per CU
    for (int L = 0; L < NLAUNCH; ++L) {
        float4* iS = (L & 1) ? set1 : set0;
        float4* oS = (L & 1) ? set0 : set1;
        fused_kernel<<<grid, 256, 0, stream>>>(ws, sig, iS, oS, out, L);
    }
}

// Round 13
// 373.179 us; speedup vs baseline: 2.1899x; 1.0489x over previous
//
#include <hip/hip_runtime.h>

// Spatially varying anisotropic 2D elastic wave sim, 384x384, 192 steps.
// Round 12: intra-block TLP — 2 waves/SIMD inside one barrier-synced block.
//  - 256 blocks (1/CU) x 512 threads (8 waves = 2/SIMD): when one wave
//    stalls on LDS latency/barrier arrival its SIMD-sibling issues VALU
//    (R10 counters: step loop ~70% wait, no pipe saturated)
//  - staging 64x48 (HALO rows 20, cols 12), OWN 24x24, patch 2x3/thread,
//    K=12, 16 launches; LDS 2x64x49 v2f = 50KB; live VGPR ~170 < 256 cap
//  - final-step LDS publish skipped (nobody reads it)
//  - all R8 machinery kept: float4 packed coeffs/state, sig preload,
//    lgkm-only barrier, packed v2f update chain (absmax-verified)

typedef float v2f __attribute__((ext_vector_type(2)));

#define NXg 384
#define NYg 384
#define NPT (NXg * NYg)
#define NFRAMES 48

#define OWN 24
#define HALOR 20       // row halo (20 >= K, integer-fit price)
#define HALOC 12       // col halo
#define TSR 64         // staging rows
#define TSC 48         // staging cols
#define KSTEPS 12
#define NLAUNCH 16
#define SCOL 49        // LDS row stride in v2f

#define H_   1e-4
#define DT_  5e-9
#define RHO_ 1610.0

#define B11_LO 5e10f
#define B11_HI 2.5e11f
#define B22_LO 5e9f
#define B22_HI 5e10f
#define B12_LO 5e9f
#define B12_HI 5e10f
#define B16_LO 0.0f
#define B16_HI 6e10f
#define B26_LO 0.0f
#define B26_HI 2e10f
#define B66_LO 5e9f
#define B66_HI 3e10f

static __device__ __constant__ float kScale  = (float)(DT_ * DT_ / (H_ * H_) / RHO_);
static __device__ __constant__ float kSrcScl = (float)(DT_ * DT_ / RHO_);

__device__ __forceinline__ float clipf(float v, float lo, float hi) {
    return fminf(fmaxf(v, lo), hi);
}
__device__ __forceinline__ v2f vfma(v2f a, v2f b, v2f c) {
    return __builtin_elementwise_fma(a, b, c);
}
__device__ __forceinline__ v2f vbc(float s) { v2f r; r[0] = s; r[1] = s; return r; }
__device__ __forceinline__ v2f vswap(v2f a) { return __builtin_shufflevector(a, a, 1, 0); }

// barrier that only waits LDS (no vmcnt drain)
#define LDS_BARRIER() asm volatile("s_waitcnt lgkmcnt(0)\n\ts_barrier" ::: "memory")

// ws float layout:
// [0..4NPT):    C0 = float4{A11, A22, A12p66, A16}  (pre-scaled)
// [4NPT..8NPT): C1 = float4{A26, A66, GS, 0}
// [8NPT..12NPT):  state set0: float4{cur.x, cur.y, old.x, old.y}
// [12NPT..16NPT): state set1

__global__ __launch_bounds__(256)
void setup_kernel(const float* __restrict__ lc11, const float* __restrict__ lc12,
                  const float* __restrict__ lc16, const float* __restrict__ lc22,
                  const float* __restrict__ lc26, const float* __restrict__ lc66,
                  const float* __restrict__ gauss, float* __restrict__ ws) {
    int i = blockIdx.x * blockDim.x + threadIdx.x;
    if (i >= NPT) return;
    float C11 = clipf(expf(lc11[i]), B11_LO, B11_HI);
    float C12 = clipf(expf(lc12[i]), B12_LO, B12_HI);
    float C16 = clipf(expf(lc16[i]), B16_LO, B16_HI);
    float C22 = clipf(expf(lc22[i]), B22_LO, B22_HI);
    float C26 = clipf(expf(lc26[i]), B26_LO, B26_HI);
    float C66 = clipf(expf(lc66[i]), B66_LO, B66_HI);
    float s = kScale;
    float4* C0 = (float4*)ws;
    float4* C1 = (float4*)(ws + 4 * (size_t)NPT);
    C0[i] = make_float4(C11 * s, C22 * s, (C12 + C66) * s, C16 * s);
    C1[i] = make_float4(C26 * s, C66 * s, gauss[i] * kSrcScl, 0.0f);
    float4* s0 = (float4*)(ws + 8 * (size_t)NPT);
    s0[i] = make_float4(0.0f, 0.0f, 0.0f, 0.0f);
}

__global__ __launch_bounds__(512)
void fused_kernel(const float* __restrict__ ws, const float* __restrict__ sig,
                  const float4* __restrict__ inS, float4* __restrict__ outS,
                  float* __restrict__ out, int L) {
    __shared__ v2f sb[2][TSR][SCOL];

    const int tid = threadIdx.x;           // 0..511
    const int rg = tid >> 4;               // 0..31 row group (2 rows each)
    const int cg = tid & 15;               // 0..15 col group (3 cols each)
    const int r0 = 2 * rg;
    const int c0 = 3 * cg;
    const int gx0 = (int)blockIdx.y * OWN - HALOR;
    const int gy0 = (int)blockIdx.x * OWN - HALOC;

    const float4* __restrict__ C0 = (const float4*)ws;
    const float4* __restrict__ C1 = (const float4*)(ws + 4 * (size_t)NPT);

    v2f cur[6], old_[6];
    v2f ca[6], cb[6];                      // {A11,A66}, {A66,A22}
    float a12p66[6], a16[6], a26[6], gs[6];
    int gidx[6];

#pragma unroll
    for (int i = 0; i < 2; ++i) {
#pragma unroll
        for (int j = 0; j < 3; ++j) {
            int p = i * 3 + j;
            int gx = gx0 + r0 + i;
            int gy = gy0 + c0 + j;
            bool d = (unsigned)gx < (unsigned)NXg && (unsigned)gy < (unsigned)NYg;
            int g = d ? gx * NYg + gy : 0;
            gidx[p] = g;
            float4 st = d ? inS[g] : make_float4(0, 0, 0, 0);
            v2f c; c[0] = st.x; c[1] = st.y;
            v2f o; o[0] = st.z; o[1] = st.w;
            cur[p] = c; old_[p] = o;
            // out-of-domain -> zero coeffs => point stays exactly 0
            float4 k0 = d ? C0[g] : make_float4(0, 0, 0, 0);
            float4 k1 = d ? C1[g] : make_float4(0, 0, 0, 0);
            v2f t; t[0] = k0.x; t[1] = k1.y; ca[p] = t;   // {A11, A66}
            v2f u; u[0] = k1.y; u[1] = k0.y; cb[p] = u;   // {A66, A22}
            a12p66[p] = k0.z; a16[p] = k0.w; a26[p] = k1.x; gs[p] = k1.z;
        }
    }

    // preload all step source values
    const int t0 = L * KSTEPS;
    float sigv[KSTEPS];
#pragma unroll
    for (int k = 0; k < KSTEPS; ++k) sigv[k] = sig[t0 + k];

    // clamped halo coords (trapezoid garbage-tolerance at staging rim)
    const int rm = (r0 > 0) ? r0 - 1 : 0;
    const int rp = (r0 + 2 < TSR) ? r0 + 2 : TSR - 1;
    const int cm = (c0 > 0) ? c0 - 1 : 0;
    const int cp = (c0 + 3 < TSC) ? c0 + 3 : TSC - 1;

    // owned: staging rows [20,44) -> rg in [10,22); cols [12,36) -> cg in [4,12)
    const bool owned = (rg >= 10) && (rg < 22) && (cg >= 4) && (cg < 12);

    // publish initial values into buffer 0
#pragma unroll
    for (int i = 0; i < 2; ++i)
#pragma unroll
        for (int j = 0; j < 3; ++j)
            sb[0][r0 + i][c0 + j] = cur[i * 3 + j];
    LDS_BARRIER();

    v2f c20; c20[0] = 2.0f; c20[1] = 0.0f;
    v2f c02; c02[0] = 0.0f; c02[1] = 2.0f;
    const v2f m2 = vbc(-2.0f);
    const v2f qt = vbc(0.25f);
    const v2f two = vbc(2.0f);

#pragma unroll 1
    for (int s = 1; s <= KSTEPS; ++s) {
        const v2f (*rb)[SCOL] = sb[(s - 1) & 1];
        v2f (*wb)[SCOL] = sb[s & 1];
        v2f vsig; vsig[0] = 0.0f; vsig[1] = sigv[s - 1];

        // assemble 4x5 v2f window: own 2x3 from regs + 14 halo b64 reads
        v2f v[4][5];
#pragma unroll
        for (int i = 0; i < 2; ++i)
#pragma unroll
            for (int j = 0; j < 3; ++j)
                v[i + 1][j + 1] = cur[i * 3 + j];
        v[0][0] = rb[rm][cm];  v[0][4] = rb[rm][cp];
        v[3][0] = rb[rp][cm];  v[3][4] = rb[rp][cp];
#pragma unroll
        for (int j = 0; j < 3; ++j) {
            v[0][j + 1] = rb[rm][c0 + j];
            v[3][j + 1] = rb[rp][c0 + j];
        }
        v[1][0] = rb[r0][cm];      v[1][4] = rb[r0][cp];
        v[2][0] = rb[r0 + 1][cm];  v[2][4] = rb[r0 + 1][cp];

        // horizontal differences shared across the 6 points' cross-derivs
        v2f dh[4][3];
#pragma unroll
        for (int i = 0; i < 4; ++i)
#pragma unroll
            for (int j = 0; j < 3; ++j)
                dh[i][j] = v[i][j + 2] - v[i][j];

#pragma unroll
        for (int i = 0; i < 2; ++i)
#pragma unroll
            for (int j = 0; j < 3; ++j) {
                int p = i * 3 + j;
                int pi = i + 1, pj = j + 1;
                v2f c = v[pi][pj];
                v2f sxx = vfma(m2, c, v[pi - 1][pj] + v[pi + 1][pj]);  // pk
                v2f syy = vfma(m2, c, v[pi][pj - 1] + v[pi][pj + 1]);  // pk
                v2f sxy = qt * (dh[pi + 1][j] - dh[pi - 1][j]);        // pk

                v2f t4 = vfma(c20, vbc(sxy[0]), vswap(sxx));
                v2f t5 = vfma(c02, vbc(sxy[1]), vswap(syy));
                v2f Lv = ca[p] * sxx;
                Lv = vfma(cb[p], syy, Lv);
                Lv = vfma(vbc(a12p66[p]), vswap(sxy), Lv);
                Lv = vfma(vbc(a16[p]), t4, Lv);
                Lv = vfma(vbc(a26[p]), t5, Lv);
                Lv = vfma(vsig, vbc(gs[p]), Lv);     // {lux, sig*gs + luy}
                v2f n = vfma(two, c, Lv) - old_[p];
                old_[p] = c;
                cur[p] = n;
            }

        // frame output at global t = t0 + s - 1; t%4==3 <=> s%4==0
        // (fire-and-forget: step barrier does NOT drain vmcnt)
        if ((s & 3) == 0 && owned) {
            int f = 3 * L + (s >> 2) - 1;
            float* oux = out + (size_t)f * NPT;
            float* ouy = out + (size_t)(NFRAMES + f) * NPT;
#pragma unroll
            for (int p = 0; p < 6; ++p) {
                oux[gidx[p]] = cur[p][0];
                ouy[gidx[p]] = cur[p][1];
            }
        }

        // publish for next step; skip on the final step (nobody reads it)
        if (s < KSTEPS) {
#pragma unroll
            for (int i = 0; i < 2; ++i)
#pragma unroll
                for (int j = 0; j < 3; ++j)
                    wb[r0 + i][c0 + j] = cur[i * 3 + j];
            LDS_BARRIER();
        }
    }

    if (owned) {
#pragma unroll
        for (int p = 0; p < 6; ++p) {
            float4 st = make_float4(cur[p][0], cur[p][1], old_[p][0], old_[p][1]);
            outS[gidx[p]] = st;
        }
    }
}

extern "C" void kernel_launch(void* const* d_in, const int* in_sizes, int n_in,
                              void* d_out, int out_size, void* d_ws, size_t ws_size,
                              hipStream_t stream) {
    const float* lc11  = (const float*)d_in[0];
    const float* lc12  = (const float*)d_in[1];
    const float* lc16  = (const float*)d_in[2];
    const float* lc22  = (const float*)d_in[3];
    const float* lc26  = (const float*)d_in[4];
    const float* lc66  = (const float*)d_in[5];
    const float* gauss = (const float*)d_in[6];
    const float* sig   = (const float*)d_in[7];

    float* ws  = (float*)d_ws;
    float* out = (float*)d_out;

    setup_kernel<<<(NPT + 255) / 256, 256, 0, stream>>>(lc11, lc12, lc16, lc22,
                                                        lc26, lc66, gauss, ws);

    float4* set0 = (float4*)(ws + 8 * (size_t)NPT);
    float4* set1 = (float4*)(ws + 12 * (size_t)NPT);

    dim3 grid(NYg / OWN, NXg / OWN);  // 16x16 = 256 blocks, 1 per CU
    for (int L = 0; L < NLAUNCH; ++L) {
        float4* iS = (L & 1) ? set1 : set0;
        float4* oS = (L & 1) ? set0 : set1;
        fused_kernel<<<grid, 512, 0, stream>>>(ws, sig, iS, oS, out, L);
    }
}